// Round 17
// baseline (134.375 us; speedup 1.0000x reference)
//
#include <hip/hip_runtime.h>

// Per-sample depthwise 7x7 cross-correlation, NHWC, SAME padding.
// inputs:  [B,H,W,C] fp32, kernels: [B,7,7,C] fp32, out: [B,H,W,C] fp32.
// out[b,y,x,c] = sum_{i,j} in[b, y+i-3, x+j-3, c] * ker[b,i,j,c]  (zero pad)
//
// R17 = R16 (XPT=8, v_pk_fma_f16 fp16-accum, pre-broadcast weights in LDS)
// at DOUBLE OCCUPANCY: 512-thread blocks (XG=4), YSPLIT=8 (YROWS=16),
// GRID=1024 -> 4 blocks/CU x 8 waves = 32 waves/CU (8/SIMD) vs R16's 16.
// R14 proved 32 waves/CU helps at XPT=4; R16 proved XPT=8 issue-efficiency
// at 16 waves/CU; this stacks both. Cost: y-halo fetch 1.375x (~+16% FETCH).
// Per-thread structure identical to R16 -> stays in the 64-VGPR tier.

#define BB 32
#define HH 128
#define WW 128
#define CC 128
#define KH 7
#define KW 7

#define XPT 8                        // x outputs per thread (4 half2 pairs)
#define NTAP (XPT + KW - 1)          // 14 tap columns per thread
#define XG 4                         // x-groups per block (512 threads / 128 c)
#define SLABW (XG * XPT)             // 32 output columns per block
#define NXS (WW / SLABW)             // 4 x-slabs
#define YSPLIT 8
#define YROWS (HH / YSPLIT)          // 16 output rows per block
#define GRID (BB * NXS * YSPLIT)     // 1024 blocks = 4 per CU (32 waves/CU)
#define WSTRIDE 60                   // per-c weight uints (7 rows x 8 + pad)
#define NPASS (YROWS + KH - 1)       // 22 single-row passes

typedef _Float16 half2_t __attribute__((ext_vector_type(2)));

static __device__ __forceinline__ half2_t pk(float a, float b) {
#if __has_builtin(__builtin_amdgcn_cvt_pkrtz)
    return __builtin_bit_cast(half2_t, __builtin_amdgcn_cvt_pkrtz(a, b));
#else
    half2_t r; r.x = (_Float16)a; r.y = (_Float16)b; return r;
#endif
}

static __device__ __forceinline__ half2_t bc(unsigned u) {
    return __builtin_bit_cast(half2_t, u);
}

__global__ __launch_bounds__(512) void crossconv_kernel(
    const float* __restrict__ in,
    const float* __restrict__ ker,
    float* __restrict__ out)
{
    __shared__ unsigned lds_w[CC * WSTRIDE];   // 30720 B

    const int tid = threadIdx.x;
    const int c  = tid & (CC - 1);   // lanes contiguous in c -> coalesced
    const int xg = __builtin_amdgcn_readfirstlane(tid >> 7);   // 0..3, wave-uniform

    // Bijective XCD swizzle (GRID=1024, 128 blocks/XCD = 4 whole samples).
    const int bid = blockIdx.x;
    const int swz = (bid & 7) * (GRID / 8) + (bid >> 3);
    const int b  = swz >> 5;         // 32 blocks per sample (4 xs x 8 yh)
    const int xs = (swz >> 3) & 3;
    const int yh = swz & 7;
    const int x0 = xs * SLABW + xg * XPT;  // wave-uniform (scalar)
    const int y0 = yh * YROWS;

    // Stage PRE-BROADCAST weights into LDS: f = i*7+j (0..48) ->
    // lds_w[c*60 + i*8 + j] = (w_f, w_f) packed fp16.
    {
        const float* kb = ker + ((size_t)b * KH * KW) * CC + c;
        for (int f = xg; f < KH * KW; f += XG) {
            const int i = f / KW, j = f - i * KW;
            const float wv = kb[f * CC];
            lds_w[c * WSTRIDE + i * 8 + j] =
                __builtin_bit_cast(unsigned, pk(wv, wv));
        }
    }
    __syncthreads();

    const float* ib = in  + ((size_t)b * HH * WW) * CC;
    float*       ob = out + ((size_t)b * HH * WW) * CC;
    const unsigned* wp = &lds_w[c * WSTRIDE];

    const bool interior = (x0 >= 3) && (x0 + NTAP - 3 < WW);

    // Tap loads rebased to column x0+2: offsets (j-5)*512 B for j=0..12 fall
    // in [-2560, 3584] (13-bit imm); t[13] via a second base.
    auto load_taps = [&](float* t, int yi) {
        if (yi < 0 || yi >= HH) {
            #pragma unroll
            for (int j = 0; j < NTAP; ++j) t[j] = 0.0f;
            return;
        }
        const float* base = ib + (size_t)yi * WW * CC + (x0 + 2) * CC + c;
        if (interior) {
            #pragma unroll
            for (int j = 0; j < 13; ++j)
                t[j] = base[(j - 5) * CC];                 // imm offsets
            t[13] = (base + 8 * CC)[0];
        } else {
            #pragma unroll
            for (int j = 0; j < NTAP; ++j) {
                const int xx = x0 - 3 + j;
                t[j] = (xx >= 0 && xx < WW) ? base[(j - 5) * CC] : 0.0f;
            }
        }
    };

    // Sliding ring: acc[s][q] = half2 partials for outputs (x0+2q, x0+2q+1)
    // of output row y = yi-3+s.
    half2_t acc[KH][XPT / 2];
    #pragma unroll
    for (int s = 0; s < KH; ++s)
        #pragma unroll
        for (int q = 0; q < XPT / 2; ++q) acc[s][q] = half2_t{0, 0};

    const int yi0 = y0 - 3;

    // Packed tap pairs p[m] = (t[m], t[m+1]), m=0..12:
    // even m=2k from cvt_pkrtz; odd m=2k+1 via alignbit(p[2k+2], p[2k]).
    // Output pair q uses p[2q+j], j=0..6.
    float t[NTAP];
    half2_t p[13];
    auto pack = [&]() {
        #pragma unroll
        for (int k = 0; k < 7; ++k) p[2 * k] = pk(t[2 * k], t[2 * k + 1]);
        #pragma unroll
        for (int k = 0; k < 6; ++k)
            p[2 * k + 1] = __builtin_bit_cast(half2_t, __builtin_amdgcn_alignbit(
                               __builtin_bit_cast(unsigned, p[2 * k + 2]),
                               __builtin_bit_cast(unsigned, p[2 * k]), 16));
    };

    load_taps(t, yi0);
    pack();

    #pragma unroll 1
    for (int pp = 0; pp < NPASS; ++pp) {
        const int yi = yi0 + pp;

        // Issue next row's tap loads; the dot pass hides the latency.
        load_taps(t, (pp + 1 < NPASS) ? (yi + 1) : HH);

        // Keep per-pass LDS weight reads in the loop (hoisting 49 broadcast
        // pairs would blow the 64-VGPR tier and spill).
        asm volatile("" ::: "memory");

        #pragma unroll
        for (int i = 0; i < KH; ++i) {
            const uint4 q0 = *(const uint4*)(wp + i * 8);      // w0..w3 bcast
            const uint4 q1 = *(const uint4*)(wp + i * 8 + 4);  // w4..w6 bcast
            const int s = 6 - i;
            #pragma unroll
            for (int q = 0; q < XPT / 2; ++q) {
                half2_t a = acc[s][q];
                a = bc(q0.x) * p[2 * q + 0] + a;
                a = bc(q0.y) * p[2 * q + 1] + a;
                a = bc(q0.z) * p[2 * q + 2] + a;
                a = bc(q0.w) * p[2 * q + 3] + a;
                a = bc(q1.x) * p[2 * q + 4] + a;
                a = bc(q1.y) * p[2 * q + 5] + a;
                a = bc(q1.z) * p[2 * q + 6] + a;
                acc[s][q] = a;
            }
        }

        const int y = yi - 3;
        if (y >= y0) {                       // upper bound guaranteed by loop end
            float* orow = ob + ((size_t)y * WW + x0) * CC + c;
            #pragma unroll
            for (int q = 0; q < XPT / 2; ++q) {
                orow[(2 * q) * CC]     = (float)acc[0][q].x;
                orow[(2 * q + 1) * CC] = (float)acc[0][q].y;
            }
        }

        // Shift ring, open fresh top slot.
        #pragma unroll
        for (int s = 0; s < KH - 1; ++s)
            #pragma unroll
            for (int q = 0; q < XPT / 2; ++q) acc[s][q] = acc[s + 1][q];
        #pragma unroll
        for (int q = 0; q < XPT / 2; ++q) acc[KH - 1][q] = half2_t{0, 0};

        // Pack the prefetched row for the next pass.
        pack();
    }
}

extern "C" void kernel_launch(void* const* d_in, const int* in_sizes, int n_in,
                              void* d_out, int out_size, void* d_ws, size_t ws_size,
                              hipStream_t stream) {
    const float* in  = (const float*)d_in[0];
    const float* ker = (const float*)d_in[1];
    float*       out = (float*)d_out;

    crossconv_kernel<<<GRID, 512, 0, stream>>>(in, ker, out);
}